// Round 8
// baseline (270.480 us; speedup 1.0000x reference)
//
#include <hip/hip_runtime.h>

// TemporalDenoise: bidirectional per-channel EMA, averaged.
// R8: LDS-free register scan with shuffle carry propagation.
//  - EMA linearity: chunk scanned with zero init + correction by true carry.
//    Carries: F(ch) = le(ch-1) + d^8 F(ch-1); truncated 4-term sum (err d^32
//    ~1e-5) -> 4 __shfl_up replace the per-thread 16-step LDS warm-up.
//  - Thread (cgi,ch) owns an 8-step chunk of 4 channels: ax[8] + fr[8] regs.
//  - Wave-edge history (16 steps, matches R7 halo semantics incl. clamped
//    seed -> exact at t=0/t=T-1): computed redundantly by ALL lanes; the 8
//    same-cgi lanes read the SAME address -> 1 cacheline per halo load.
//  - No LDS, no barriers, no vmcnt asm. __launch_bounds__(64,4) caps VGPR
//    <=128 -> 16 waves/CU (2x R7's LDS-capped 8).
// Plain stores (nt stores cost +25% WRITE_SIZE, R3).

#define BB 32
#define TT 2048
#define CGALL 128           // f32x4 groups per (b,t) row (512 ch)
#define CGT 8               // f32x4 groups per wave = 32 ch = 128B per t
#define NCGT (CGALL / CGT)  // 16
#define LCH 8               // time steps per thread
#define NCHW 8              // chunks per wave
#define TB (LCH * NCHW)     // 64 time steps per wave
#define NTB (TT / TB)       // 32
#define HALO 16

typedef float f32x4 __attribute__((ext_vector_type(4)));

static __device__ __forceinline__ f32x4 fma4(const f32x4 a, const f32x4 b,
                                             const f32x4 c) {
  f32x4 r;
  r.x = fmaf(a.x, b.x, c.x);
  r.y = fmaf(a.y, b.y, c.y);
  r.z = fmaf(a.z, b.z, c.z);
  r.w = fmaf(a.w, b.w, c.w);
  return r;
}

static __device__ __forceinline__ f32x4 shfl4(const f32x4 v, int srcLane) {
  const int s = srcLane & 63;
  f32x4 r;
  r.x = __shfl(v.x, s, 64);
  r.y = __shfl(v.y, s, 64);
  r.z = __shfl(v.z, s, 64);
  r.w = __shfl(v.w, s, 64);
  return r;
}

__global__ __launch_bounds__(64, 4) void ema_bidir_kernel(
    const f32x4* __restrict__ x, const f32x4* __restrict__ alogit4,
    f32x4* __restrict__ out) {
  const int bid = blockIdx.x;
  const int cgt = bid & (NCGT - 1);        // channel tile (fastest)
  const int tb = (bid >> 4) & (NTB - 1);   // time tile
  const int b = bid >> 9;                  // batch

  const int lane = threadIdx.x;  // 0..63
  const int cgi = lane & 7;      // channel group within tile
  const int ch = lane >> 3;      // chunk within wave (0..7)

  const int t0w = tb * TB;         // wave tile start
  const int t0 = t0w + ch * LCH;   // chunk start

  const f32x4* xr = x + ((size_t)b * TT) * CGALL + cgt * CGT + cgi;
  f32x4* orow = out + ((size_t)b * TT) * CGALL + cgt * CGT + cgi;

  const f32x4 al = alogit4[cgt * CGT + cgi];
  f32x4 a, d;
  a.x = 1.0f / (1.0f + __expf(-al.x));
  a.y = 1.0f / (1.0f + __expf(-al.y));
  a.z = 1.0f / (1.0f + __expf(-al.z));
  a.w = 1.0f / (1.0f + __expf(-al.w));
  d.x = 1.0f - a.x; d.y = 1.0f - a.y; d.z = 1.0f - a.z; d.w = 1.0f - a.w;
  const f32x4 d2 = d * d, d4 = d2 * d2;
  const f32x4 d8 = d4 * d4, d16 = d8 * d8, d24 = d16 * d8;

  // ---- own chunk loads, pre-scaled: ax[i] = a * x[t0+i] ----
  f32x4 ax[LCH];
#pragma unroll
  for (int i = 0; i < LCH; ++i) ax[i] = a * xr[(size_t)(t0 + i) * CGALL];

  // ---- wave-edge histories, all lanes redundantly (1 line per load) ----
  f32x4 Hf;  // fwd value at time t0w-1 (true carry into chunk 0)
  {
    int t = t0w - HALO;
    f32x4 c = xr[(size_t)(t < 0 ? 0 : t) * CGALL];
#pragma unroll
    for (int k = 1; k < HALO; ++k) {
      int tt = t0w - HALO + k;
      c = fma4(a, xr[(size_t)(tt < 0 ? 0 : tt) * CGALL], d * c);
    }
    Hf = c;
  }
  f32x4 Hb;  // bwd value at time t0w+TB (true carry into chunk 7)
  {
    int t = t0w + TB + HALO - 1;
    f32x4 c = xr[(size_t)(t > TT - 1 ? TT - 1 : t) * CGALL];
#pragma unroll
    for (int k = 1; k < HALO; ++k) {
      int tt = t0w + TB + HALO - 1 - k;
      c = fma4(a, xr[(size_t)(tt > TT - 1 ? TT - 1 : tt) * CGALL], d * c);
    }
    Hb = c;
  }

  // ---- zero-init local ends ----
  // le  = fwd local end  = sum_k d^(7-k) ax[k]  (scan form)
  // ble = bwd local end  = sum_k d^k     ax[k]
  f32x4 le = ax[0];
  f32x4 ble = ax[0];
  f32x4 p = d;
#pragma unroll
  for (int i = 1; i < LCH; ++i) {
    le = fma4(d, le, ax[i]);
    ble = fma4(p, ax[i], ble);
    p = p * d;
  }

  const f32x4 vzero = {0.f, 0.f, 0.f, 0.f};
  const f32x4 vone = {1.f, 1.f, 1.f, 1.f};

  // ---- fwd carry-in via 4-term truncated chain + history term ----
  f32x4 F;
  {
    const f32x4 s1 = shfl4(le, lane - 8);
    const f32x4 s2 = shfl4(le, lane - 16);
    const f32x4 s3 = shfl4(le, lane - 24);
    const f32x4 s4 = shfl4(le, lane - 32);
    const f32x4 t1 = (ch >= 1) ? s1 : vzero;
    const f32x4 t2 = (ch >= 2) ? s2 : vzero;
    const f32x4 t3 = (ch >= 3) ? s3 : vzero;
    const f32x4 t4 = (ch >= 4) ? s4 : vzero;
    const f32x4 hc = (ch == 0) ? vone
                   : (ch == 1) ? d8
                   : (ch == 2) ? d16
                   : (ch == 3) ? d24 : vzero;
    F = fma4(d8, t2, t1);
    F = fma4(d16, t3, F);
    F = fma4(d24, t4, F);
    F = fma4(hc, Hf, F);
  }

  // ---- bwd carry-in (mirror, shuffle down) ----
  f32x4 B;
  {
    const f32x4 s1 = shfl4(ble, lane + 8);
    const f32x4 s2 = shfl4(ble, lane + 16);
    const f32x4 s3 = shfl4(ble, lane + 24);
    const f32x4 s4 = shfl4(ble, lane + 32);
    const f32x4 t1 = (ch <= 6) ? s1 : vzero;
    const f32x4 t2 = (ch <= 5) ? s2 : vzero;
    const f32x4 t3 = (ch <= 4) ? s3 : vzero;
    const f32x4 t4 = (ch <= 3) ? s4 : vzero;
    const f32x4 hc = (ch == 7) ? vone
                   : (ch == 6) ? d8
                   : (ch == 5) ? d16
                   : (ch == 4) ? d24 : vzero;
    B = fma4(d8, t2, t1);
    B = fma4(d16, t3, B);
    B = fma4(d24, t4, B);
    B = fma4(hc, Hb, B);
  }

  // ---- pass 2: true scans + fused averaged store ----
  f32x4 fr[LCH];
  f32x4 c = F;
#pragma unroll
  for (int i = 0; i < LCH; ++i) {
    c = fma4(d, c, ax[i]);
    fr[i] = c;
  }
  c = B;
#pragma unroll
  for (int i = LCH - 1; i >= 0; --i) {
    c = fma4(d, c, ax[i]);
    const f32x4 s = fr[i] + c;
    f32x4 r;
    r.x = 0.5f * s.x; r.y = 0.5f * s.y; r.z = 0.5f * s.z; r.w = 0.5f * s.w;
    orow[(size_t)(t0 + i) * CGALL] = r;
  }
}

extern "C" void kernel_launch(void* const* d_in, const int* in_sizes, int n_in,
                              void* d_out, int out_size, void* d_ws,
                              size_t ws_size, hipStream_t stream) {
  const f32x4* x = (const f32x4*)d_in[0];
  const f32x4* alogit4 = (const f32x4*)d_in[1];
  f32x4* out = (f32x4*)d_out;

  const int grid = BB * NCGT * NTB;  // 16384 blocks x 64 threads
  ema_bidir_kernel<<<grid, 64, 0, stream>>>(x, alogit4, out);
}

// Round 9
// 49.652 us; speedup vs baseline: 5.4476x; 5.4476x over previous
//
#include <hip/hip_runtime.h>

// TemporalDenoise: bidirectional per-channel EMA, averaged.
// R9 = R8 (LDS-free register scan + shuffle carry propagation) with the
// register economics fixed:
//  - R8's __launch_bounds__(64,4) empirically imposed a 64-VGPR budget ->
//    ax[8]+fr[8] spilled to scratch = +488MB HBM writes, 270us. Now (64,2):
//    budget >=128 under either second-arg interpretation.
//  - Horner carry chain folds the history term into the shuffle terms:
//    term_m = (ch>=m) ? le(ch-m) : (ch==m-1 ? H : 0), m=1..4
//    F = t1 + d8*(t2 + d8*(t3 + d8*t4))   (truncation err d8^4 ~ 1e-5)
//    -> only d8 stays live (no d16/d24/hc registers).
// Structure: thread (cgi,ch) owns an 8-step chunk of 4 channels. Wave-edge
// histories (16 clamped steps, exact at t=0/t=T-1) computed redundantly by
// all lanes (8 same-address lanes -> 1 cacheline per halo load). No LDS,
// no barriers. Plain stores (nt stores cost +25% WRITE_SIZE, R3).

#define BB 32
#define TT 2048
#define CGALL 128           // f32x4 groups per (b,t) row (512 ch)
#define CGT 8               // f32x4 groups per wave = 32 ch
#define NCGT (CGALL / CGT)  // 16
#define LCH 8               // time steps per thread
#define NCHW 8              // chunks per wave
#define TB (LCH * NCHW)     // 64 time steps per wave
#define NTB (TT / TB)       // 32
#define HALO 16

typedef float f32x4 __attribute__((ext_vector_type(4)));

static __device__ __forceinline__ f32x4 fma4(const f32x4 a, const f32x4 b,
                                             const f32x4 c) {
  f32x4 r;
  r.x = fmaf(a.x, b.x, c.x);
  r.y = fmaf(a.y, b.y, c.y);
  r.z = fmaf(a.z, b.z, c.z);
  r.w = fmaf(a.w, b.w, c.w);
  return r;
}

static __device__ __forceinline__ f32x4 shfl4(const f32x4 v, int srcLane) {
  const int s = srcLane & 63;
  f32x4 r;
  r.x = __shfl(v.x, s, 64);
  r.y = __shfl(v.y, s, 64);
  r.z = __shfl(v.z, s, 64);
  r.w = __shfl(v.w, s, 64);
  return r;
}

__global__ __launch_bounds__(64, 2) void ema_bidir_kernel(
    const f32x4* __restrict__ x, const f32x4* __restrict__ alogit4,
    f32x4* __restrict__ out) {
  const int bid = blockIdx.x;
  const int cgt = bid & (NCGT - 1);       // channel tile (fastest)
  const int tb = (bid >> 4) & (NTB - 1);  // time tile
  const int b = bid >> 9;                 // batch

  const int lane = threadIdx.x;  // 0..63
  const int cgi = lane & 7;      // channel group within tile
  const int ch = lane >> 3;      // chunk within wave (0..7)

  const int t0w = tb * TB;        // wave tile start
  const int t0 = t0w + ch * LCH;  // chunk start

  const f32x4* xr = x + ((size_t)b * TT) * CGALL + cgt * CGT + cgi;
  f32x4* orow = out + ((size_t)b * TT) * CGALL + cgt * CGT + cgi;

  const f32x4 al = alogit4[cgt * CGT + cgi];
  f32x4 a, d;
  a.x = 1.0f / (1.0f + __expf(-al.x));
  a.y = 1.0f / (1.0f + __expf(-al.y));
  a.z = 1.0f / (1.0f + __expf(-al.z));
  a.w = 1.0f / (1.0f + __expf(-al.w));
  d.x = 1.0f - a.x; d.y = 1.0f - a.y; d.z = 1.0f - a.z; d.w = 1.0f - a.w;
  const f32x4 d2 = d * d, d4 = d2 * d2;
  const f32x4 d8 = d4 * d4;

  // ---- own chunk loads, pre-scaled: ax[i] = a * x[t0+i] ----
  f32x4 ax[LCH];
#pragma unroll
  for (int i = 0; i < LCH; ++i) ax[i] = a * xr[(size_t)(t0 + i) * CGALL];

  // ---- wave-edge histories (redundant across lanes; 1 line per load) ----
  f32x4 Hf;  // fwd value at time t0w-1
  {
    int t = t0w - HALO;
    f32x4 c = xr[(size_t)(t < 0 ? 0 : t) * CGALL];
#pragma unroll
    for (int k = 1; k < HALO; ++k) {
      int tt = t0w - HALO + k;
      c = fma4(a, xr[(size_t)(tt < 0 ? 0 : tt) * CGALL], d * c);
    }
    Hf = c;
  }
  f32x4 Hb;  // bwd value at time t0w+TB
  {
    int t = t0w + TB + HALO - 1;
    f32x4 c = xr[(size_t)(t > TT - 1 ? TT - 1 : t) * CGALL];
#pragma unroll
    for (int k = 1; k < HALO; ++k) {
      int tt = t0w + TB + HALO - 1 - k;
      c = fma4(a, xr[(size_t)(tt > TT - 1 ? TT - 1 : tt) * CGALL], d * c);
    }
    Hb = c;
  }

  // ---- zero-init local ends ----
  f32x4 le = ax[0];   // fwd local end  = sum_k d^(7-k) ax[k]
  f32x4 ble = ax[0];  // bwd local end  = sum_k d^k     ax[k]
  {
    f32x4 p = d;
#pragma unroll
    for (int i = 1; i < LCH; ++i) {
      le = fma4(d, le, ax[i]);
      ble = fma4(p, ax[i], ble);
      p = p * d;
    }
  }

  const f32x4 vzero = {0.f, 0.f, 0.f, 0.f};

  // ---- fwd carry-in: Horner over 4 shuffle terms, history folded in ----
  f32x4 F;
  {
    const f32x4 s1 = shfl4(le, lane - 8);
    const f32x4 s2 = shfl4(le, lane - 16);
    const f32x4 s3 = shfl4(le, lane - 24);
    const f32x4 s4 = shfl4(le, lane - 32);
    const f32x4 t1 = (ch >= 1) ? s1 : Hf;                       // m=1
    const f32x4 t2 = (ch >= 2) ? s2 : ((ch == 1) ? Hf : vzero); // m=2
    const f32x4 t3 = (ch >= 3) ? s3 : ((ch == 2) ? Hf : vzero); // m=3
    const f32x4 t4 = (ch >= 4) ? s4 : ((ch == 3) ? Hf : vzero); // m=4
    F = fma4(d8, t4, t3);
    F = fma4(d8, F, t2);
    F = fma4(d8, F, t1);
  }

  // ---- bwd carry-in (mirror) ----
  f32x4 B;
  {
    const f32x4 s1 = shfl4(ble, lane + 8);
    const f32x4 s2 = shfl4(ble, lane + 16);
    const f32x4 s3 = shfl4(ble, lane + 24);
    const f32x4 s4 = shfl4(ble, lane + 32);
    const f32x4 t1 = (ch <= 6) ? s1 : Hb;
    const f32x4 t2 = (ch <= 5) ? s2 : ((ch == 6) ? Hb : vzero);
    const f32x4 t3 = (ch <= 4) ? s3 : ((ch == 5) ? Hb : vzero);
    const f32x4 t4 = (ch <= 3) ? s4 : ((ch == 4) ? Hb : vzero);
    B = fma4(d8, t4, t3);
    B = fma4(d8, B, t2);
    B = fma4(d8, B, t1);
  }

  // ---- pass 2: true scans + fused averaged store ----
  f32x4 fr[LCH];
  f32x4 c = F;
#pragma unroll
  for (int i = 0; i < LCH; ++i) {
    c = fma4(d, c, ax[i]);
    fr[i] = c;
  }
  c = B;
#pragma unroll
  for (int i = LCH - 1; i >= 0; --i) {
    c = fma4(d, c, ax[i]);
    const f32x4 s = fr[i] + c;
    f32x4 r;
    r.x = 0.5f * s.x; r.y = 0.5f * s.y; r.z = 0.5f * s.z; r.w = 0.5f * s.w;
    orow[(size_t)(t0 + i) * CGALL] = r;
  }
}

extern "C" void kernel_launch(void* const* d_in, const int* in_sizes, int n_in,
                              void* d_out, int out_size, void* d_ws,
                              size_t ws_size, hipStream_t stream) {
  const f32x4* x = (const f32x4*)d_in[0];
  const f32x4* alogit4 = (const f32x4*)d_in[1];
  f32x4* out = (f32x4*)d_out;

  const int grid = BB * NCGT * NTB;  // 16384 blocks x 64 threads
  ema_bidir_kernel<<<grid, 64, 0, stream>>>(x, alogit4, out);
}